// Round 10
// baseline (360.014 us; speedup 1.0000x reference)
//
#include <hip/hip_runtime.h>
#include <hip/hip_bf16.h>
#include <stdint.h>

#define BATCH 128
#define SEQ   512
#define NW    6
#define DIM   64
#define NELEM (BATCH * SEQ * NW)   // 393216
#define PI_F  3.14159265358979323846f

typedef float v2f __attribute__((ext_vector_type(2)));
typedef uint16_t u16x8 __attribute__((ext_vector_type(8)));

__device__ __forceinline__ v2f pkfma(float s, v2f m, v2f a) {
    return __builtin_elementwise_fma((v2f){s, s}, m, a);
}

// Single-instruction DPP add stage (bound_ctrl=true folds to v_add_f32_dpp).
template <int CTRL>
__device__ __forceinline__ float dpp_add(float v) {
    return v + __int_as_float(__builtin_amdgcn_update_dpp(
        0, __float_as_int(v), CTRL, 0xF, 0xF, true));
}

// 6-way interleaved reduction stage (r8-verified: shr1,2,4,8 + bcast15,31
// -> totals land in lane 63).
template <int CTRL>
__device__ __forceinline__ void red6(float v[6]) {
#pragma unroll
    for (int k = 0; k < 6; ++k) v[k] = dpp_add<CTRL>(v[k]);
}

// DPP move, bound_ctrl=true (all CTRLs used valid on every lane).
template <int CTRL>
__device__ __forceinline__ float dpp_mov(float x) {
    return __int_as_float(__builtin_amdgcn_update_dpp(
        0, __float_as_int(x), CTRL, 0xF, 0xF, true));
}

__device__ __forceinline__ float ldf(const void* p, int i, bool bf) {
    if (bf) {
        uint32_t u = (uint32_t)((const uint16_t*)p)[i];
        return __uint_as_float(u << 16);
    }
    return ((const float*)p)[i];
}

// ---------------------------------------------------------------------------
// Kernel 1 (msetup + misc): unchanged from r8.
// ---------------------------------------------------------------------------
__global__ void k_prep(const void* ang, const void* poly, const void* fp,
                       const void* bp, const void* fc, const void* bc,
                       float* __restrict__ misc, float* __restrict__ Mg,
                       int* __restrict__ flag) {
    __shared__ int cnt;
    if (threadIdx.x == 0) cnt = 0;
    __syncthreads();
    {
        uint32_t w = ((const uint32_t*)ang)[threadIdx.x & 255];
        uint32_t e = (w >> 8) & 0xFFu;
        if (e >= 0x3Au && e <= 0x41u) atomicAdd(&cnt, 1);
    }
    __syncthreads();
    const bool bf = (cnt >= 128);

    if (blockIdx.x == 32) {
        if (threadIdx.x == 0)      misc[76] = ldf(fc, 0, bf);
        else if (threadIdx.x == 1) misc[77] = ldf(bc, 0, bf);
        else if (threadIdx.x == 2) *flag = bf ? 1 : 0;
        return;
    }

    const int lane = threadIdx.x & 63;
    const int tix  = blockIdx.x * 4 + (threadIdx.x >> 6);
    const int dir  = tix >> 6;
    const int col  = tix & 63;
    const void* prm = dir ? bp : fp;
    const int p = lane;

    float yr = (p == col) ? 1.f : 0.f;
    float yi = 0.f;

#pragma unroll
    for (int d = 0; d < 4; ++d) {
        const float th = 0.5f * PI_F * ldf(poly, d, bf) *
                         (float)(6 - 2 * (int)__popc((unsigned)p));
        float s, c;
        __sincosf(th, &s, &c);
        const float nr = yr * c + yi * s;
        const float ni = yi * c - yr * s;
        yr = nr; yi = ni;
#pragma unroll
        for (int k = 0; k < 6; ++k) {
            const int cw = k, tw = (k + 1) % 6;
            const int src = p ^ (((p >> (5 - cw)) & 1) << (5 - tw));
            yr = __shfl(yr, src, 64);
            yi = __shfl(yi, src, 64);
        }
    }

    int idx = 0;
#pragma unroll
    for (int l = 0; l < 2; ++l) {
#pragma unroll
        for (int w = 0; w < 6; ++w) {
            float cx, sx, cy, sy, cz, sz;
            __sincosf(0.5f * ldf(prm, idx + 0, bf), &sx, &cx);
            __sincosf(0.5f * ldf(prm, idx + 1, bf), &sy, &cy);
            __sincosf(0.5f * ldf(prm, idx + 2, bf), &sz, &cz);
            idx += 3;
            const float A = cy * cx, B = sy * sx, C = sy * cx, D = cy * sx;
            const float U00r = cz * A + sz * B, U00i = cz * B - sz * A;
            const float U11r = U00r,            U11i = sz * A - cz * B;
            const float Xr   = cz * C + sz * D, Xi   = sz * C - cz * D;
            const int m  = 1 << (5 - w);
            const int bb = (p >> (5 - w)) & 1;
            const float C1r = bb ? U11r : U00r;
            const float C1i = bb ? U11i : U00i;
            const float C2r = bb ? Xr : -Xr;
            const float C2i = Xi;
            const float pr = __shfl_xor(yr, m, 64);
            const float pi = __shfl_xor(yi, m, 64);
            const float nr = C1r * yr - C1i * yi + C2r * pr - C2i * pi;
            const float ni = C1r * yi + C1i * yr + C2r * pi + C2i * pr;
            yr = nr; yi = ni;
        }
#pragma unroll
        for (int k = 0; k < 5; ++k) {
            const int src = p ^ (((p >> (5 - k)) & 1) << (5 - (k + 1)));
            yr = __shfl(yr, src, 64);
            yi = __shfl(yi, src, 64);
        }
    }

    float* out = Mg + ((size_t)(dir * 64 + p) * 64 + (size_t)col) * 2;
    out[0] = yr;
    out[1] = yi;
}

// ---------------------------------------------------------------------------
// Kernel 2: recurrent sim — TWO waves/chain (the untested wave-split point):
//   * M split by column halves: wave w holds cols 32w..32w+31 (64 VGPRs —
//     UNDER the proven 132 arch-VGPR ceiling, so register-resident like the
//     4-wave split; no AGPR parking possible).
//   * halves every exchange term that pins the 4-wave design: barrier syncs
//     2 waves (half the skew), ONE partner ds_read_b64 (was 3), 2 combine
//     adds (was 6), drain covers 1 producer.
//   * cost: matvec partial 20->36 pkfma + replicated e-build — but r0/r6/r8
//     proved issue-count changes don't move time (stall-dominated).
//   * measurement/dots/tree/readlane/xq-prefetch: r8-verbatim (verified).
// ---------------------------------------------------------------------------
__global__ void __launch_bounds__(128, 1) k_sim(const void* __restrict__ ang,
                                                const float* __restrict__ Mg,
                                                float* __restrict__ hbuf,
                                                const int* __restrict__ flag) {
    const int tid   = threadIdx.x;
    const int lane  = tid & 63;
    const int wv    = tid >> 6;              // wave 0..1
    const int chain = blockIdx.x;            // 0..255
    const int dir   = chain >> 7;
    const int b     = chain & 127;
    const bool bf   = (*flag != 0);

    __shared__ __align__(16) float  cl[SEQ * 12];   // 24 KB cos/sin(x)
    __shared__ __align__(16) float  zb[SEQ * NW];   // 12 KB output buffer
    __shared__ float2 pY[2][2][DIM];                // ping-pong partials, 2 KB

    // ---- stage: convert this chain's 3072 angles -> cos/sin in LDS ----
    if (!bf) {
        const float4* src =
            (const float4*)((const float*)ang + (size_t)b * (SEQ * NW));
#pragma unroll
        for (int k = 0; k < 6; ++k) {
            const int v = k * 128 + tid;          // float4 index 0..767
            const float4 a = src[v];
            __align__(16) float o[8];
            float s, c;
            __sincosf(a.x, &s, &c); o[0] = c; o[1] = s;
            __sincosf(a.y, &s, &c); o[2] = c; o[3] = s;
            __sincosf(a.z, &s, &c); o[4] = c; o[5] = s;
            __sincosf(a.w, &s, &c); o[6] = c; o[7] = s;
            ((float4*)cl)[2 * v]     = ((const float4*)o)[0];
            ((float4*)cl)[2 * v + 1] = ((const float4*)o)[1];
        }
    } else {
        const u16x8* src =
            (const u16x8*)((const uint16_t*)ang + (size_t)b * (SEQ * NW));
#pragma unroll
        for (int k = 0; k < 3; ++k) {
            const int v = k * 128 + tid;          // u16x8 index 0..383
            const u16x8 a = src[v];
            __align__(16) float o[16];
#pragma unroll
            for (int e = 0; e < 8; ++e) {
                const float x = __uint_as_float(((uint32_t)a[e]) << 16);
                float s, c;
                __sincosf(x, &s, &c);
                o[2 * e] = c; o[2 * e + 1] = s;
            }
#pragma unroll
            for (int j = 0; j < 4; ++j)
                ((float4*)cl)[4 * v + j] = ((const float4*)o)[j];
        }
    }

    // ---- my 32 resident M columns: row = lane, cols = 32wv..32wv+31 ----
    v2f Mres[32];
    {
        const float2* mr2 =
            (const float2*)(Mg + (size_t)(dir * 64 + lane) * 128 + 64 * wv);
#pragma unroll
        for (int k = 0; k < 32; ++k) Mres[k] = (v2f){mr2[k].x, mr2[k].y};
    }

    // per-wire Z sign masks
    int zmask[6];
#pragma unroll
    for (int w = 0; w < 6; ++w) zmask[w] = ((lane >> (5 - w)) & 1) << 31;
    const int ow = wv ^ 1;                   // the other wave

    float h[6] = {0.f, 0.f, 0.f, 0.f, 0.f, 0.f};

    // encode h -> my 32-col matvec partial.
    // e[col] = eH[col>>3]·eL[col&7]; wave w needs eH[4w+a], a=0..3:
    //   eH[4w+a] = g01[2w+(a>>1)] · ((a&1)? sw2 : cw2),
    //   g01[2w+j] = (w? sw0 : cw0) · (j? sw1 : cw1)   (wave-uniform select)
    auto encode_matvec = [&](v2f& acc) {
        const v2f kc1 = {2.6041667e-3f, 2.6041667e-3f};
        const v2f kc0 = {-0.125f, -0.125f};
        const v2f ks1 = {2.6041667e-4f, 2.6041667e-4f};
        const v2f ks0 = {-2.0833333e-2f, -2.0833333e-2f};
        const v2f one = {1.f, 1.f}, half = {0.5f, 0.5f};
        v2f hp0 = {h[0], h[1]}, hp1 = {h[2], h[3]}, hp2 = {h[4], h[5]};
        v2f u0 = hp0 * hp0, u1 = hp1 * hp1, u2 = hp2 * hp2;
        v2f c0 = __builtin_elementwise_fma(u0,
                    __builtin_elementwise_fma(u0, kc1, kc0), one);
        v2f c1 = __builtin_elementwise_fma(u1,
                    __builtin_elementwise_fma(u1, kc1, kc0), one);
        v2f c2 = __builtin_elementwise_fma(u2,
                    __builtin_elementwise_fma(u2, kc1, kc0), one);
        v2f s0 = hp0 * __builtin_elementwise_fma(u0,
                    __builtin_elementwise_fma(u0, ks1, ks0), half);
        v2f s1 = hp1 * __builtin_elementwise_fma(u1,
                    __builtin_elementwise_fma(u1, ks1, ks0), half);
        v2f s2 = hp2 * __builtin_elementwise_fma(u2,
                    __builtin_elementwise_fma(u2, ks1, ks0), half);
        // wires: 0:(c0.x,s0.x) 1:(c0.y,s0.y) 2:(c1.x,s1.x)
        //        3:(c1.y,s1.y) 4:(c2.x,s2.x) 5:(c2.y,s2.y)
        const float t0 = wv ? s0.x : c0.x;           // wire0 bit = wv
        const float gA = t0 * c0.y, gB = t0 * s0.y;  // g01[2w], g01[2w+1]
        float eH4[4];
        eH4[0] = gA * c1.x; eH4[1] = gA * s1.x;
        eH4[2] = gB * c1.x; eH4[3] = gB * s1.x;
        float g45[4], eL[8];
        g45[0] = c2.x * c2.y; g45[1] = c2.x * s2.y;
        g45[2] = s2.x * c2.y; g45[3] = s2.x * s2.y;
#pragma unroll
        for (int j = 0; j < 8; ++j)
            eL[j] = ((j >> 2) ? s1.y : c1.y) * g45[j & 3];
        v2f y = {0.f, 0.f};
#pragma unroll
        for (int a = 0; a < 4; ++a) {
            v2f T = {0.f, 0.f};
#pragma unroll
            for (int jl = 0; jl < 8; ++jl)
                T = pkfma(eL[jl], Mres[8 * a + jl], T);
            y = pkfma(eH4[a], T, y);
        }
        acc = y;
    };

    // walking pointers
    const float* cp = cl + (dir ? (SEQ - 1) * 12 : 0);
    const int   cstep = dir ? -12 : 12;
    float*       zp = zb + (dir ? (SEQ - 1) * NW : 0);
    const int   zstep = dir ? -NW : NW;

    __syncthreads();                         // staging visible

    // ---- peel: partial for t=0 (h=0) + xq preload for t=0 ----
    v2f myacc;
    encode_matvec(myacc);
    pY[0][wv][lane] = (float2){myacc.x, myacc.y};
    float4 xq0 = ((const float4*)cp)[0];
    float4 xq1 = ((const float4*)cp)[1];
    float4 xq2 = ((const float4*)cp)[2];
    cp += cstep;
    __syncthreads();                         // pY[0] visible

    for (int t = 0; t < SEQ; ++t) {
        const int buf = t & 1;

        // reassemble full y: ONE partner partial + my own
        const float2 yP = pY[buf][ow][lane];
        const float yr = myacc.x + yP.x;
        const float yi = myacc.y + yP.y;
        const int yri = __float_as_int(yr), yii = __float_as_int(yi);

        // dots y[l]·y[l^m] (r8-verified, all VALU)
        float dot[6];
        {   // w0: xor32 — d'*s' = y[l]*y[l^32] on every lane
            auto rr = __builtin_amdgcn_permlane32_swap(yri, yri, false, false);
            auto ri = __builtin_amdgcn_permlane32_swap(yii, yii, false, false);
            dot[0] = fmaf(__int_as_float((int)rr[0]), __int_as_float((int)rr[1]),
                          __int_as_float((int)ri[0]) * __int_as_float((int)ri[1]));
        }
        {   // w1: xor16
            auto rr = __builtin_amdgcn_permlane16_swap(yri, yri, false, false);
            auto ri = __builtin_amdgcn_permlane16_swap(yii, yii, false, false);
            dot[1] = fmaf(__int_as_float((int)rr[0]), __int_as_float((int)rr[1]),
                          __int_as_float((int)ri[0]) * __int_as_float((int)ri[1]));
        }
        dot[2] = fmaf(yr, dpp_mov<0x128>(yr), yi * dpp_mov<0x128>(yi)); // xor8
        dot[3] = fmaf(yr, dpp_mov<0x141>(dpp_mov<0x1B>(yr)),            // xor4
                      yi * dpp_mov<0x141>(dpp_mov<0x1B>(yi)));
        dot[4] = fmaf(yr, dpp_mov<0x4E>(yr), yi * dpp_mov<0x4E>(yi));   // xor2
        dot[5] = fmaf(yr, dpp_mov<0xB1>(yr), yi * dpp_mov<0xB1>(yi));   // xor1

        const float q = fmaf(yr, yr, yi * yi);
        const float cx[6] = {xq0.x, xq0.z, xq1.x, xq1.z, xq2.x, xq2.z};
        const float sx[6] = {xq0.y, xq0.w, xq1.y, xq1.w, xq2.y, xq2.w};

        // per-lane contribution to z_w = cx*Z_w - sx*X_w (r8-verified)
        float v[6];
#pragma unroll
        for (int w = 0; w < 6; ++w) {
            const float cq = __int_as_float(__float_as_int(cx[w] * q) ^ zmask[w]);
            v[w] = fmaf(-sx[w], dot[w], cq);
        }

        // xq for step t+1 — off the critical path
        if (t + 1 < SEQ) {
            xq0 = ((const float4*)cp)[0];
            xq1 = ((const float4*)cp)[1];
            xq2 = ((const float4*)cp)[2];
            cp += cstep;
        }

        // to-lane-63 tree (r8-verified sequence)
        red6<0x111>(v);   // row_shr:1
        red6<0x112>(v);   // row_shr:2
        red6<0x114>(v);   // row_shr:4
        red6<0x118>(v);   // row_shr:8
        red6<0x142>(v);   // row_bcast:15
        red6<0x143>(v);   // row_bcast:31

        if (tid == 63) {                     // lane 63 holds the totals
#pragma unroll
            for (int w = 0; w < 6; ++w) zp[w] = v[w];
        }
        zp += zstep;
#pragma unroll
        for (int w = 0; w < 6; ++w)          // broadcast (r8-verified)
            h[w] = __int_as_float(
                __builtin_amdgcn_readlane(__float_as_int(v[w]), 63));

        // next state's partial into the other buffer
        encode_matvec(myacc);
        pY[buf ^ 1][wv][lane] = (float2){myacc.x, myacc.y};
        __syncthreads();                     // the ONLY barrier per step
    }

    // ---- bulk store outputs: 768 float4 over 128 threads ----
    {
        const float4* zs4 = (const float4*)zb;
        float4* go = (float4*)(hbuf + (size_t)dir * NELEM +
                               (size_t)b * (SEQ * NW));
#pragma unroll
        for (int k = 0; k < 6; ++k) {
            const int idx = tid + k * 128;
            go[idx] = zs4[idx];
        }
    }
}

// ---------------------------------------------------------------------------
// Kernel 3: out = sigmoid(fc)*h_fwd + sigmoid(bc)*h_bwd, dtype per flag.
// ---------------------------------------------------------------------------
__global__ void k_combine(const float* __restrict__ hbuf,
                          const float* __restrict__ misc,
                          void* __restrict__ out, const int* __restrict__ flag) {
    const int i = blockIdx.x * blockDim.x + threadIdx.x;
    if (i >= NELEM) return;
    const float sf = 1.f / (1.f + __expf(-misc[76]));
    const float sb = 1.f / (1.f + __expf(-misc[77]));
    const float v = sf * hbuf[i] + sb * hbuf[NELEM + i];
    if (*flag) ((__hip_bfloat16*)out)[i] = __float2bfloat16(v);
    else       ((float*)out)[i] = v;
}

// ---------------------------------------------------------------------------
extern "C" void kernel_launch(void* const* d_in, const int* in_sizes, int n_in,
                              void* d_out, int out_size, void* d_ws, size_t ws_size,
                              hipStream_t stream) {
    const void* ang  = d_in[0];
    const void* poly = d_in[1];
    const void* fp   = d_in[2];
    const void* bp   = d_in[3];
    const void* fc   = d_in[4];
    const void* bc   = d_in[5];

    // ws (floats): pad[32] | misc[128] | hbuf[2*NELEM] | Mg[16384] | flag
    float* misc = (float*)d_ws + 32;
    float* hbuf = misc + 128;
    float* Mg   = hbuf + 2 * NELEM;
    int*   flag = (int*)(Mg + 2 * 64 * 64 * 2);

    k_prep<<<33, 256, 0, stream>>>(ang, poly, fp, bp, fc, bc, misc, Mg, flag);
    k_sim<<<256, 128, 0, stream>>>(ang, Mg, hbuf, flag);
    k_combine<<<(NELEM + 255) / 256, 256, 0, stream>>>(hbuf, misc, d_out, flag);
}